// Round 7
// baseline (258.146 us; speedup 1.0000x reference)
//
#include <hip/hip_runtime.h>
#include <cmath>
#include <cstdint>

#define NB 8
#define NPTS 4096
#define NPOINT 204
#define NCENT (NB * NPOINT)   // 1632
#define NTASK (5 * NCENT)     // 8160

typedef unsigned long long u64;

struct BallParams { float thr[5]; int ns[5]; float el; float denom; };
struct FinalParams { double w[5]; };

// Candidate: packed (f32-dist-bits << 32)|(4095-idx) key + the point's coords.
// All selects key off the exact u64 compare -> bit-identical argmax semantics
// (value-major, first-index tie-break), coords ride along.
struct C5 { u64 k; float x, y, z; };
__device__ __forceinline__ C5 cmax(C5 a, C5 b) { return a.k > b.k ? a : b; }

template<int CTRL, int RMASK>
__device__ __forceinline__ C5 dpp_cmax_step(C5 v) {
    const int lo = (int)(unsigned)v.k, hi = (int)(unsigned)(v.k >> 32);
    const int xi = __float_as_int(v.x), yi = __float_as_int(v.y), zi = __float_as_int(v.z);
    const int lo2 = __builtin_amdgcn_update_dpp(lo, lo, CTRL, RMASK, 0xF, false);
    const int hi2 = __builtin_amdgcn_update_dpp(hi, hi, CTRL, RMASK, 0xF, false);
    const int x2  = __builtin_amdgcn_update_dpp(xi, xi, CTRL, RMASK, 0xF, false);
    const int y2  = __builtin_amdgcn_update_dpp(yi, yi, CTRL, RMASK, 0xF, false);
    const int z2  = __builtin_amdgcn_update_dpp(zi, zi, CTRL, RMASK, 0xF, false);
    C5 o;
    o.k = ((u64)(unsigned)hi2 << 32) | (unsigned)lo2;
    o.x = __int_as_float(x2); o.y = __int_as_float(y2); o.z = __int_as_float(z2);
    return o.k > v.k ? o : v;
}
__device__ __forceinline__ C5 wave_cmax63(C5 v) {
    v = dpp_cmax_step<0x111, 0xF>(v);   // row_shr:1
    v = dpp_cmax_step<0x112, 0xF>(v);   // row_shr:2
    v = dpp_cmax_step<0x114, 0xF>(v);   // row_shr:4
    v = dpp_cmax_step<0x118, 0xF>(v);   // row_shr:8
    v = dpp_cmax_step<0x142, 0xA>(v);   // row_bcast:15
    v = dpp_cmax_step<0x143, 0xC>(v);   // row_bcast:31
    return v;                            // lane 63 holds wave max
}

// ---------------------------------------------------------------------------
// Fused: blocks 0..7 FPS (one batch, 8 waves, 8 pts/lane, coords carried
// through the reduction -> zero LDS reads of point data on the critical path);
// blocks 8..519 repulsion (float4 LDS, 2 blocks/CU as in R4-best).
// ---------------------------------------------------------------------------
__global__ __launch_bounds__(512) void fused_fps_rep(const float* __restrict__ pcd,
                                                     int* __restrict__ fps,
                                                     double* __restrict__ part)
{
#pragma clang fp contract(off)
    __shared__ float4 spts[NPTS];                 // 64 KiB (rep branch only)
    __shared__ int fps_lds[NPOINT];
    __shared__ __align__(16) uint4 exchA[2][8];   // key.lo, key.hi, xbits, ybits
    __shared__ __align__(16) float exchZ[2][8];   // z
    __shared__ double wsum[8];

    const int t = threadIdx.x;
    const int lane = t & 63, wv = t >> 6;

    if (blockIdx.x < NB) {
        // ------------------------------ FPS ------------------------------
        const int b = blockIdx.x;
        const float* base = pcd + (size_t)b * NPTS * 3;

        const int pbase = t * 8;
        float px[8], py[8], pz[8], md[8];
#pragma unroll
        for (int k = 0; k < 8; ++k) {
            px[k] = base[(pbase + k) * 3 + 0];
            py[k] = base[(pbase + k) * 3 + 1];
            pz[k] = base[(pbase + k) * 3 + 2];
            md[k] = 1e10f;
        }
        if (t == 0) fps_lds[0] = 0;

        float lx = base[0], ly = base[1], lz = base[2];
        __syncthreads();

        for (int it = 1; it < NPOINT; ++it) {
            C5 c[8];
            // exact per-element: (dx^2+dy^2)+dz^2, fminf
#pragma unroll
            for (int k = 0; k < 8; ++k) {
                const float dx = px[k] - lx, dy = py[k] - ly, dz = pz[k] - lz;
                float d = dx * dx + dy * dy;
                d = d + dz * dz;
                const float m = fminf(md[k], d);
                md[k] = m;
                c[k].k = ((u64)(unsigned)__float_as_int(m) << 32)
                       | (unsigned)(4095 - (pbase + k));
                c[k].x = px[k]; c[k].y = py[k]; c[k].z = pz[k];
            }
            // per-lane tree (static indices -> stays in registers)
            c[0] = cmax(c[0], c[4]); c[1] = cmax(c[1], c[5]);
            c[2] = cmax(c[2], c[6]); c[3] = cmax(c[3], c[7]);
            c[0] = cmax(c[0], c[2]); c[1] = cmax(c[1], c[3]);
            c[0] = cmax(c[0], c[1]);
            const C5 w = wave_cmax63(c[0]);

            const int p = it & 1;
            if (lane == 63) {
                exchA[p][wv] = make_uint4((unsigned)w.k, (unsigned)(w.k >> 32),
                                          (unsigned)__float_as_int(w.x),
                                          (unsigned)__float_as_int(w.y));
                exchZ[p][wv] = w.z;
            }
            __syncthreads();

            // every thread combines the 8 wave candidates (broadcast reads)
            const float4 z03 = ((const float4*)&exchZ[p][0])[0];
            const float4 z47 = ((const float4*)&exchZ[p][0])[1];
            C5 a0, a1, a2, a3, a4, a5, a6, a7;
            {
                const uint4 A0 = exchA[p][0], A1 = exchA[p][1];
                const uint4 A2 = exchA[p][2], A3 = exchA[p][3];
                const uint4 A4 = exchA[p][4], A5 = exchA[p][5];
                const uint4 A6 = exchA[p][6], A7 = exchA[p][7];
                a0.k = ((u64)A0.y << 32) | A0.x; a0.x = __int_as_float(A0.z); a0.y = __int_as_float(A0.w); a0.z = z03.x;
                a1.k = ((u64)A1.y << 32) | A1.x; a1.x = __int_as_float(A1.z); a1.y = __int_as_float(A1.w); a1.z = z03.y;
                a2.k = ((u64)A2.y << 32) | A2.x; a2.x = __int_as_float(A2.z); a2.y = __int_as_float(A2.w); a2.z = z03.z;
                a3.k = ((u64)A3.y << 32) | A3.x; a3.x = __int_as_float(A3.z); a3.y = __int_as_float(A3.w); a3.z = z03.w;
                a4.k = ((u64)A4.y << 32) | A4.x; a4.x = __int_as_float(A4.z); a4.y = __int_as_float(A4.w); a4.z = z47.x;
                a5.k = ((u64)A5.y << 32) | A5.x; a5.x = __int_as_float(A5.z); a5.y = __int_as_float(A5.w); a5.z = z47.y;
                a6.k = ((u64)A6.y << 32) | A6.x; a6.x = __int_as_float(A6.z); a6.y = __int_as_float(A6.w); a6.z = z47.z;
                a7.k = ((u64)A7.y << 32) | A7.x; a7.x = __int_as_float(A7.z); a7.y = __int_as_float(A7.w); a7.z = z47.w;
            }
            a0 = cmax(a0, a1); a2 = cmax(a2, a3);
            a4 = cmax(a4, a5); a6 = cmax(a6, a7);
            a0 = cmax(a0, a2); a4 = cmax(a4, a6);
            a0 = cmax(a0, a4);

            const int bi = 4095 - (int)((unsigned)a0.k & 0xFFFu);
            if (t == 0) fps_lds[it] = bi;
            lx = a0.x; ly = a0.y; lz = a0.z;
        }
        __syncthreads();
        for (int j = t; j < NPOINT; j += 512) fps[b * NPOINT + j] = fps_lds[j];
    } else {
        // --------------------------- repulsion ---------------------------
        const int bb = blockIdx.x - NB;
        const int batch = bb >> 6;
        const int chunk = bb & 63;
        const float* base = pcd + (size_t)batch * NPTS * 3;

        for (int j = t; j < NPTS; j += 512) {
            const float x = base[j * 3 + 0], y = base[j * 3 + 1], z = base[j * 3 + 2];
            const float qs = (x * x + y * y) + z * z;
            spts[j] = make_float4(x, y, z, qs);
        }
        __syncthreads();

        const float h = 0.0005f;
        double acc = 0.0;

        for (int ii = 0; ii < 8; ++ii) {
            const int i = (chunk << 6) + (wv << 3) + ii;
            const float4 C = spts[i];
            const float cx = C.x, cy = C.y, cz = C.z, cs = C.w;
            float s0 = 3e38f, s1 = 3e38f, s2 = 3e38f, s3 = 3e38f;
            for (int bj = 0; bj < NPTS; bj += 64) {
                const int j = bj + lane;
                const float4 o = spts[j];
                const float dot = (cx * o.x + cy * o.y) + cz * o.z;
                const float d = fmaxf((cs + o.w) - 2.0f * dot, 0.0f);
                const bool q = (d < h) && (j != i);
                unsigned long long bal = __ballot(q);
                while (bal) {
                    const int src = __ffsll((unsigned long long)bal) - 1;
                    bal &= bal - 1;
                    const float dv = __shfl(d, src);
                    if (dv < s0) { s3 = s2; s2 = s1; s1 = s0; s0 = dv; }
                    else if (dv < s1) { s3 = s2; s2 = s1; s1 = dv; }
                    else if (dv < s2) { s3 = s2; s2 = dv; }
                    else if (dv < s3) { s3 = dv; }
                }
            }
            if (lane == 0) {
                if (s0 < h) acc += (double)(h - s0);
                if (s1 < h) acc += (double)(h - s1);
                if (s2 < h) acc += (double)(h - s2);
                if (s3 < h) acc += (double)(h - s3);
            }
        }
        if (lane == 0) wsum[wv] = acc;
        __syncthreads();
        if (t == 0) {
            double s = 0.0;
            for (int w = 0; w < 8; ++w) s += wsum[w];
            part[bb] = s;
        }
    }
}

// ---------------------------------------------------------------------------
// Ball query + per-group uniform term. 4 waves/block; all 4 tasks of a block
// share one (p, batch) since NPOINT%4==0 -> shared LDS staging of the batch.
// ---------------------------------------------------------------------------
__global__ __launch_bounds__(256) void ball_kernel(const float* __restrict__ pcd,
                                                   const int* __restrict__ fps,
                                                   double* __restrict__ uvals,
                                                   BallParams P)
{
#pragma clang fp contract(off)
    __shared__ float4 spts[NPTS];        // 64 KiB: x,y,z,|q|^2
    __shared__ int wlist[4][64];
    __shared__ float4 gpts[4][64];

    const int wave = threadIdx.x >> 6;
    const int lane = threadIdx.x & 63;
    const int task0 = blockIdx.x * 4;            // all 4 tasks: same pi, same b
    const int pi = task0 / NCENT;
    const int c0 = task0 % NCENT;
    const int b  = c0 / NPOINT;
    const int   nsample = P.ns[pi];
    const float thr     = P.thr[pi];

    const float* base = pcd + (size_t)b * NPTS * 3;
    for (int j = threadIdx.x; j < NPTS; j += 256) {
        const float x = base[j * 3 + 0], y = base[j * 3 + 1], z = base[j * 3 + 2];
        const float qs = (x * x + y * y) + z * z;
        spts[j] = make_float4(x, y, z, qs);
    }
    __syncthreads();

    const int c = c0 + wave;
    const int m = c % NPOINT;
    const int ci = fps[b * NPOINT + m];
    const float4 C = spts[ci];
    const float cx = C.x, cy = C.y, cz = C.z, cs = C.w;

    int cnt = 0;
    for (int bj = 0; bj < NPTS; bj += 64) {
        const int j = bj + lane;
        const float4 o = spts[j];
        const float dot = (cx * o.x + cy * o.y) + cz * o.z;
        const float d = fmaxf((cs + o.w) - 2.0f * dot, 0.0f);
        const bool q = d < thr;
        const unsigned long long bal = __ballot(q);
        if (q) {
            const int pos = cnt + __popcll(bal & ((1ull << lane) - 1ull));
            if (pos < nsample) wlist[wave][pos] = j;
        }
        cnt += __popcll(bal);
        if (cnt >= nsample) break;
    }
    const int m_in = (cnt < nsample) ? cnt : nsample;   // >= 1 (center inside)

    const int gidx = wlist[wave][(lane < m_in) ? lane : 0];
    const float4 G = spts[gidx];
    gpts[wave][lane] = G;
    const float gx = G.x, gy = G.y, gz = G.z, gs = G.w;

    float m1 = 3.0e38f, m2 = 3.0e38f;
    for (int j = 0; j < nsample; ++j) {
        const float4 o = gpts[wave][j];
        const float dot = (gx * o.x + gy * o.y) + gz * o.z;
        const float d = fmaxf((gs + o.w) - 2.0f * dot, 0.0f);
        if (d < m1) { m2 = m1; m1 = d; }
        else if (d < m2) { m2 = d; }
    }
    float ud = (lane < nsample) ? fabsf(sqrtf(m2 + 1e-12f) + 1e-8f) : 0.0f;
    for (int off = 32; off; off >>= 1) ud += __shfl_xor(ud, off);
    if (lane == 0) {
        const float um   = ud / (float)nsample;
        const float diff = um - P.el;
        const float u    = (diff * diff) / P.denom;
        uvals[pi * NCENT + c] = (double)u;
    }
}

// ---------------------------------------------------------------------------
// Deterministic final reduction + loss assembly.
// ---------------------------------------------------------------------------
__global__ __launch_bounds__(256) void final_kernel(const double* __restrict__ uvals,
                                                    const double* __restrict__ part,
                                                    float* __restrict__ out,
                                                    FinalParams F)
{
    __shared__ double red[256];
    const int t = threadIdx.x;
    double sums[6];

    for (int p = 0; p < 5; ++p) {
        double s = 0.0;
        for (int c = t; c < NCENT; c += 256) s += uvals[p * NCENT + c];
        red[t] = s;
        __syncthreads();
        for (int o = 128; o; o >>= 1) {
            if (t < o) red[t] += red[t + o];
            __syncthreads();
        }
        if (t == 0) sums[p] = red[0];
        __syncthreads();
    }
    {
        double s = 0.0;
        for (int c = t; c < NB * 64; c += 256) s += part[c];
        red[t] = s;
        __syncthreads();
        for (int o = 128; o; o >>= 1) {
            if (t < o) red[t] += red[t + o];
            __syncthreads();
        }
        if (t == 0) sums[5] = red[0];
    }
    if (t == 0) {
        double loss = 0.0;
        loss += (sums[0] / (double)NCENT) * F.w[0];
        loss += (sums[1] / (double)NCENT) * F.w[1];
        loss += (sums[2] / (double)NCENT) * F.w[2];
        loss += (sums[3] / (double)NCENT) * F.w[3];
        loss += (sums[4] / (double)NCENT) * F.w[4];
        loss /= 5.0;
        const double rep = sums[5] / (double)(NB * NPTS * 4);
        out[0] = (float)(loss + rep);
    }
}

// ---------------------------------------------------------------------------
extern "C" void kernel_launch(void* const* d_in, const int* in_sizes, int n_in,
                              void* d_out, int out_size, void* d_ws, size_t ws_size,
                              hipStream_t stream)
{
    const float* pcd = (const float*)d_in[0];
    float* out = (float*)d_out;

    int*    fps   = (int*)d_ws;                                   // NB*NPOINT ints
    double* uvals = (double*)((char*)d_ws + 8192);                // 5*NCENT doubles
    double* repp  = (double*)((char*)d_ws + 8192 + (size_t)5 * NCENT * 8); // NB*64 doubles

    const double pv[5] = {0.004, 0.006, 0.008, 0.01, 0.012};
    const int    nsv[5] = {16, 24, 32, 40, 49};

    BallParams bp;
    FinalParams fp;
    for (int i = 0; i < 5; ++i) {
        const double r = sqrt(pv[i]);
        bp.thr[i] = (float)(r * r);
        bp.ns[i]  = nsv[i];
        const double w = pv[i] * 100.0;
        fp.w[i] = w * w;
    }
    const double el = sqrt(3.141592653589793 / 4096.0);
    bp.el    = (float)el;
    bp.denom = (float)(el + 1e-8);

    fused_fps_rep<<<NB + NB * 64, 512, 0, stream>>>(pcd, fps, repp);
    ball_kernel<<<NTASK / 4, 256, 0, stream>>>(pcd, fps, uvals, bp);
    final_kernel<<<1, 256, 0, stream>>>(uvals, repp, out, fp);
}

// Round 8
// 241.022 us; speedup vs baseline: 1.0710x; 1.0710x over previous
//
#include <hip/hip_runtime.h>
#include <cmath>
#include <cstdint>

#define NB 8
#define NPTS 4096
#define NPOINT 204
#define NCENT (NB * NPOINT)   // 1632
#define NTASK (5 * NCENT)     // 8160

typedef unsigned long long u64;

struct BallParams { float thr[5]; int ns[5]; float el; float denom; };
struct FinalParams { double w[5]; };

// ---------------------------------------------------------------------------
// u64 max DPP reduction: row_shr 1/2/4/8 + row_bcast15/31 -> lane 63 holds max.
// ---------------------------------------------------------------------------
template<int CTRL, int RMASK>
__device__ __forceinline__ u64 dpp_u64max_step(u64 v) {
    const int lo = (int)(unsigned)v, hi = (int)(unsigned)(v >> 32);
    const int lo2 = __builtin_amdgcn_update_dpp(lo, lo, CTRL, RMASK, 0xF, false);
    const int hi2 = __builtin_amdgcn_update_dpp(hi, hi, CTRL, RMASK, 0xF, false);
    const u64 o = ((u64)(unsigned)hi2 << 32) | (unsigned)lo2;
    return o > v ? o : v;
}
__device__ __forceinline__ u64 wave_u64max63(u64 v) {
    v = dpp_u64max_step<0x111, 0xF>(v);   // row_shr:1
    v = dpp_u64max_step<0x112, 0xF>(v);   // row_shr:2
    v = dpp_u64max_step<0x114, 0xF>(v);   // row_shr:4
    v = dpp_u64max_step<0x118, 0xF>(v);   // row_shr:8
    v = dpp_u64max_step<0x142, 0xA>(v);   // row_bcast:15
    v = dpp_u64max_step<0x143, 0xC>(v);   // row_bcast:31
    return v;                              // lane 63 = wave max
}
__device__ __forceinline__ u64 u64max(u64 a, u64 b) { return a > b ? a : b; }

// ---------------------------------------------------------------------------
// Fused: blocks 0..7 FPS (R4 structure, verbatim: 8 waves, 8 pts/lane);
// blocks 8..519 repulsion, register-tiled: 8 centers/wave held in regs,
// one spts[j] load serves all 8; FMA allowed (threshold-clamped term).
// ---------------------------------------------------------------------------
__global__ __launch_bounds__(512) void fused_fps_rep(const float* __restrict__ pcd,
                                                     int* __restrict__ fps,
                                                     double* __restrict__ part)
{
    __shared__ float4 spts[NPTS];                 // 64 KiB
    __shared__ int fps_lds[NPOINT];
    __shared__ __align__(16) u64 exch[2][8];
    __shared__ double wsum[8];

    const int t = threadIdx.x;
    const int lane = t & 63, wv = t >> 6;

    if (blockIdx.x < NB) {
        // ------------------------------ FPS ------------------------------
#pragma clang fp contract(off)
        const int b = blockIdx.x;
        const float* base = pcd + (size_t)b * NPTS * 3;

        for (int j = t; j < NPTS; j += 512)
            spts[j] = make_float4(base[3*j], base[3*j+1], base[3*j+2], 0.f);

        const int pbase = t * 8;
        float px[8], py[8], pz[8], md[8];
#pragma unroll
        for (int k = 0; k < 8; ++k) {
            px[k] = base[(pbase + k) * 3 + 0];
            py[k] = base[(pbase + k) * 3 + 1];
            pz[k] = base[(pbase + k) * 3 + 2];
            md[k] = 1e10f;
        }
        if (t == 0) fps_lds[0] = 0;
        __syncthreads();

        float lx = spts[0].x, ly = spts[0].y, lz = spts[0].z;

        for (int it = 1; it < NPOINT; ++it) {
            u64 c[8];
            // exact per-element: (dx^2+dy^2)+dz^2, fminf; pack (bits(md)<<32)|(4095-idx)
#pragma unroll
            for (int k = 0; k < 8; ++k) {
                const float dx = px[k] - lx, dy = py[k] - ly, dz = pz[k] - lz;
                float d = dx * dx + dy * dy;
                d = d + dz * dz;
                const float m = fminf(md[k], d);
                md[k] = m;
                c[k] = ((u64)(unsigned)__float_as_int(m) << 32)
                     | (unsigned)(4095 - (pbase + k));
            }
#pragma unroll
            for (int s = 4; s >= 1; s >>= 1)
#pragma unroll
                for (int i = 0; i < 8; ++i)
                    if (i < s) c[i] = u64max(c[i], c[i + s]);
            const u64 wmax = wave_u64max63(c[0]);

            if (lane == 63) exch[it & 1][wv] = wmax;
            __syncthreads();

            const ulonglong2* e = (const ulonglong2*)&exch[it & 1][0];
            const ulonglong2 E0 = e[0], E1 = e[1], E2 = e[2], E3 = e[3];
            u64 m01 = u64max(E0.x, E0.y), m23 = u64max(E1.x, E1.y);
            u64 m45 = u64max(E2.x, E2.y), m67 = u64max(E3.x, E3.y);
            const u64 m = u64max(u64max(m01, m23), u64max(m45, m67));
            const int bi = 4095 - (int)((unsigned)m & 0xFFFu);

            if (t == 0) fps_lds[it] = bi;
            const float4 cc = spts[bi];
            lx = cc.x; ly = cc.y; lz = cc.z;
        }
        __syncthreads();
        for (int j = t; j < NPOINT; j += 512) fps[b * NPOINT + j] = fps_lds[j];
    } else {
        // --------------------------- repulsion ---------------------------
        // FMA contraction permitted here: every contribution is clamped by
        // max(h - d, 0) with d < h = 5e-4, so 1-ulp d-perturbations move the
        // loss by < 1e-9 (boundary flips contribute ~0 by construction).
        const int bb = blockIdx.x - NB;
        const int batch = bb >> 6;
        const int chunk = bb & 63;
        const float* base = pcd + (size_t)batch * NPTS * 3;

        for (int j = t; j < NPTS; j += 512) {
            const float x = base[j * 3 + 0], y = base[j * 3 + 1], z = base[j * 3 + 2];
            const float qs = (x * x + y * y) + z * z;
            spts[j] = make_float4(x, y, z, qs);
        }
        __syncthreads();

        const float h = 0.0005f;
        const int i0 = (chunk << 6) + (wv << 3);

        float cxr[8], cyr[8], czr[8], csr[8];
        float s0[8], s1[8], s2[8], s3[8];
#pragma unroll
        for (int cc = 0; cc < 8; ++cc) {
            const float4 C = spts[i0 + cc];
            cxr[cc] = C.x; cyr[cc] = C.y; czr[cc] = C.z; csr[cc] = C.w;
            s0[cc] = 3e38f; s1[cc] = 3e38f; s2[cc] = 3e38f; s3[cc] = 3e38f;
        }

        for (int bj = 0; bj < NPTS; bj += 64) {
            const int j = bj + lane;
            const float4 o = spts[j];
#pragma unroll
            for (int cc = 0; cc < 8; ++cc) {
                const float dot = cxr[cc] * o.x + cyr[cc] * o.y + czr[cc] * o.z;
                const float d = fmaxf((csr[cc] + o.w) - 2.0f * dot, 0.0f);
                const bool q = (d < h) && (j != i0 + cc);
                unsigned long long bal = __ballot(q);
                while (bal) {
                    const int src = __ffsll((unsigned long long)bal) - 1;
                    bal &= bal - 1;
                    const float dv = __shfl(d, src);
                    if (dv < s0[cc]) { s3[cc]=s2[cc]; s2[cc]=s1[cc]; s1[cc]=s0[cc]; s0[cc]=dv; }
                    else if (dv < s1[cc]) { s3[cc]=s2[cc]; s2[cc]=s1[cc]; s1[cc]=dv; }
                    else if (dv < s2[cc]) { s3[cc]=s2[cc]; s2[cc]=dv; }
                    else if (dv < s3[cc]) { s3[cc]=dv; }
                }
            }
        }
        if (lane == 0) {
            double acc = 0.0;
#pragma unroll
            for (int cc = 0; cc < 8; ++cc) {
                if (s0[cc] < h) acc += (double)(h - s0[cc]);
                if (s1[cc] < h) acc += (double)(h - s1[cc]);
                if (s2[cc] < h) acc += (double)(h - s2[cc]);
                if (s3[cc] < h) acc += (double)(h - s3[cc]);
            }
            wsum[wv] = acc;
        }
        __syncthreads();
        if (t == 0) {
            double s = 0.0;
            for (int w = 0; w < 8; ++w) s += wsum[w];
            part[bb] = s;
        }
    }
}

// ---------------------------------------------------------------------------
// Ball query + per-group uniform term. 4 waves/block; all 4 tasks of a block
// share one (p, batch) since NPOINT%4==0 -> shared LDS staging of the batch.
// ---------------------------------------------------------------------------
__global__ __launch_bounds__(256) void ball_kernel(const float* __restrict__ pcd,
                                                   const int* __restrict__ fps,
                                                   double* __restrict__ uvals,
                                                   BallParams P)
{
#pragma clang fp contract(off)
    __shared__ float4 spts[NPTS];        // 64 KiB: x,y,z,|q|^2
    __shared__ int wlist[4][64];
    __shared__ float4 gpts[4][64];

    const int wave = threadIdx.x >> 6;
    const int lane = threadIdx.x & 63;
    const int task0 = blockIdx.x * 4;            // all 4 tasks: same pi, same b
    const int pi = task0 / NCENT;
    const int c0 = task0 % NCENT;
    const int b  = c0 / NPOINT;
    const int   nsample = P.ns[pi];
    const float thr     = P.thr[pi];

    const float* base = pcd + (size_t)b * NPTS * 3;
    for (int j = threadIdx.x; j < NPTS; j += 256) {
        const float x = base[j * 3 + 0], y = base[j * 3 + 1], z = base[j * 3 + 2];
        const float qs = (x * x + y * y) + z * z;
        spts[j] = make_float4(x, y, z, qs);
    }
    __syncthreads();

    const int c = c0 + wave;
    const int m = c % NPOINT;
    const int ci = fps[b * NPOINT + m];
    const float4 C = spts[ci];
    const float cx = C.x, cy = C.y, cz = C.z, cs = C.w;

    int cnt = 0;
    for (int bj = 0; bj < NPTS; bj += 64) {
        const int j = bj + lane;
        const float4 o = spts[j];
        const float dot = (cx * o.x + cy * o.y) + cz * o.z;
        const float d = fmaxf((cs + o.w) - 2.0f * dot, 0.0f);
        const bool q = d < thr;
        const unsigned long long bal = __ballot(q);
        if (q) {
            const int pos = cnt + __popcll(bal & ((1ull << lane) - 1ull));
            if (pos < nsample) wlist[wave][pos] = j;
        }
        cnt += __popcll(bal);
        if (cnt >= nsample) break;
    }
    const int m_in = (cnt < nsample) ? cnt : nsample;   // >= 1 (center inside)

    const int gidx = wlist[wave][(lane < m_in) ? lane : 0];
    const float4 G = spts[gidx];
    gpts[wave][lane] = G;
    const float gx = G.x, gy = G.y, gz = G.z, gs = G.w;

    float m1 = 3.0e38f, m2 = 3.0e38f;
    for (int j = 0; j < nsample; ++j) {
        const float4 o = gpts[wave][j];
        const float dot = (gx * o.x + gy * o.y) + gz * o.z;
        const float d = fmaxf((gs + o.w) - 2.0f * dot, 0.0f);
        if (d < m1) { m2 = m1; m1 = d; }
        else if (d < m2) { m2 = d; }
    }
    float ud = (lane < nsample) ? fabsf(sqrtf(m2 + 1e-12f) + 1e-8f) : 0.0f;
    for (int off = 32; off; off >>= 1) ud += __shfl_xor(ud, off);
    if (lane == 0) {
        const float um   = ud / (float)nsample;
        const float diff = um - P.el;
        const float u    = (diff * diff) / P.denom;
        uvals[pi * NCENT + c] = (double)u;
    }
}

// ---------------------------------------------------------------------------
// Deterministic final reduction + loss assembly: 6 interleaved shuffle-tree
// sums, a single barrier.
// ---------------------------------------------------------------------------
__global__ __launch_bounds__(256) void final_kernel(const double* __restrict__ uvals,
                                                    const double* __restrict__ part,
                                                    float* __restrict__ out,
                                                    FinalParams F)
{
    __shared__ double red[6][4];
    const int t = threadIdx.x;
    const int lane = t & 63, wv = t >> 6;

    double s[6] = {0.0, 0.0, 0.0, 0.0, 0.0, 0.0};
    for (int c = t; c < NCENT; c += 256) {
        s[0] += uvals[0 * NCENT + c];
        s[1] += uvals[1 * NCENT + c];
        s[2] += uvals[2 * NCENT + c];
        s[3] += uvals[3 * NCENT + c];
        s[4] += uvals[4 * NCENT + c];
    }
    for (int c = t; c < NB * 64; c += 256) s[5] += part[c];

    for (int off = 32; off; off >>= 1) {
#pragma unroll
        for (int p = 0; p < 6; ++p) s[p] += __shfl_xor(s[p], off);
    }
    if (lane == 0) {
#pragma unroll
        for (int p = 0; p < 6; ++p) red[p][wv] = s[p];
    }
    __syncthreads();
    if (t == 0) {
        double sums[6];
#pragma unroll
        for (int p = 0; p < 6; ++p)
            sums[p] = ((red[p][0] + red[p][1]) + red[p][2]) + red[p][3];
        double loss = 0.0;
        loss += (sums[0] / (double)NCENT) * F.w[0];
        loss += (sums[1] / (double)NCENT) * F.w[1];
        loss += (sums[2] / (double)NCENT) * F.w[2];
        loss += (sums[3] / (double)NCENT) * F.w[3];
        loss += (sums[4] / (double)NCENT) * F.w[4];
        loss /= 5.0;
        const double rep = sums[5] / (double)(NB * NPTS * 4);
        out[0] = (float)(loss + rep);
    }
}

// ---------------------------------------------------------------------------
extern "C" void kernel_launch(void* const* d_in, const int* in_sizes, int n_in,
                              void* d_out, int out_size, void* d_ws, size_t ws_size,
                              hipStream_t stream)
{
    const float* pcd = (const float*)d_in[0];
    float* out = (float*)d_out;

    int*    fps   = (int*)d_ws;                                   // NB*NPOINT ints
    double* uvals = (double*)((char*)d_ws + 8192);                // 5*NCENT doubles
    double* repp  = (double*)((char*)d_ws + 8192 + (size_t)5 * NCENT * 8); // NB*64 doubles

    const double pv[5] = {0.004, 0.006, 0.008, 0.01, 0.012};
    const int    nsv[5] = {16, 24, 32, 40, 49};

    BallParams bp;
    FinalParams fp;
    for (int i = 0; i < 5; ++i) {
        const double r = sqrt(pv[i]);
        bp.thr[i] = (float)(r * r);
        bp.ns[i]  = nsv[i];
        const double w = pv[i] * 100.0;
        fp.w[i] = w * w;
    }
    const double el = sqrt(3.141592653589793 / 4096.0);
    bp.el    = (float)el;
    bp.denom = (float)(el + 1e-8);

    fused_fps_rep<<<NB + NB * 64, 512, 0, stream>>>(pcd, fps, repp);
    ball_kernel<<<NTASK / 4, 256, 0, stream>>>(pcd, fps, uvals, bp);
    final_kernel<<<1, 256, 0, stream>>>(uvals, repp, out, fp);
}

// Round 9
// 177.296 us; speedup vs baseline: 1.4560x; 1.3594x over previous
//
#include <hip/hip_runtime.h>
#include <cmath>
#include <cstdint>

#define NB 8
#define NPTS 4096
#define NPOINT 204
#define NCENT (NB * NPOINT)   // 1632

typedef unsigned long long u64;

struct BallParams { float thr[5]; int ns[5]; float el; float denom; };
struct FinalParams { double w[5]; };

// ---------------------------------------------------------------------------
// u64 max DPP reduction: row_shr 1/2/4/8 + row_bcast15/31 -> lane 63 holds max.
// ---------------------------------------------------------------------------
template<int CTRL, int RMASK>
__device__ __forceinline__ u64 dpp_u64max_step(u64 v) {
    const int lo = (int)(unsigned)v, hi = (int)(unsigned)(v >> 32);
    const int lo2 = __builtin_amdgcn_update_dpp(lo, lo, CTRL, RMASK, 0xF, false);
    const int hi2 = __builtin_amdgcn_update_dpp(hi, hi, CTRL, RMASK, 0xF, false);
    const u64 o = ((u64)(unsigned)hi2 << 32) | (unsigned)lo2;
    return o > v ? o : v;
}
__device__ __forceinline__ u64 wave_u64max63(u64 v) {
    v = dpp_u64max_step<0x111, 0xF>(v);   // row_shr:1
    v = dpp_u64max_step<0x112, 0xF>(v);   // row_shr:2
    v = dpp_u64max_step<0x114, 0xF>(v);   // row_shr:4
    v = dpp_u64max_step<0x118, 0xF>(v);   // row_shr:8
    v = dpp_u64max_step<0x142, 0xA>(v);   // row_bcast:15
    v = dpp_u64max_step<0x143, 0xC>(v);   // row_bcast:31
    return v;                              // lane 63 = wave max
}
__device__ __forceinline__ u64 u64max(u64 a, u64 b) { return a > b ? a : b; }

// ---------------------------------------------------------------------------
// Fused (R4-champion structure, verbatim): blocks 0..7 FPS (8 waves, 8
// pts/lane); blocks 8..519 repulsion (one load + one ballot per j-block).
// ---------------------------------------------------------------------------
__global__ __launch_bounds__(512) void fused_fps_rep(const float* __restrict__ pcd,
                                                     int* __restrict__ fps,
                                                     double* __restrict__ part)
{
#pragma clang fp contract(off)
    __shared__ float4 spts[NPTS];                 // 64 KiB
    __shared__ int fps_lds[NPOINT];
    __shared__ __align__(16) u64 exch[2][8];
    __shared__ double wsum[8];

    const int t = threadIdx.x;
    const int lane = t & 63, wv = t >> 6;

    if (blockIdx.x < NB) {
        // ------------------------------ FPS ------------------------------
        const int b = blockIdx.x;
        const float* base = pcd + (size_t)b * NPTS * 3;

        for (int j = t; j < NPTS; j += 512)
            spts[j] = make_float4(base[3*j], base[3*j+1], base[3*j+2], 0.f);

        const int pbase = t * 8;
        float px[8], py[8], pz[8], md[8];
#pragma unroll
        for (int k = 0; k < 8; ++k) {
            px[k] = base[(pbase + k) * 3 + 0];
            py[k] = base[(pbase + k) * 3 + 1];
            pz[k] = base[(pbase + k) * 3 + 2];
            md[k] = 1e10f;
        }
        if (t == 0) fps_lds[0] = 0;
        __syncthreads();

        float lx = spts[0].x, ly = spts[0].y, lz = spts[0].z;

        for (int it = 1; it < NPOINT; ++it) {
            u64 c[8];
            // exact per-element: (dx^2+dy^2)+dz^2, fminf; pack (bits(md)<<32)|(4095-idx)
#pragma unroll
            for (int k = 0; k < 8; ++k) {
                const float dx = px[k] - lx, dy = py[k] - ly, dz = pz[k] - lz;
                float d = dx * dx + dy * dy;
                d = d + dz * dz;
                const float m = fminf(md[k], d);
                md[k] = m;
                c[k] = ((u64)(unsigned)__float_as_int(m) << 32)
                     | (unsigned)(4095 - (pbase + k));
            }
#pragma unroll
            for (int s = 4; s >= 1; s >>= 1)
#pragma unroll
                for (int i = 0; i < 8; ++i)
                    if (i < s) c[i] = u64max(c[i], c[i + s]);
            const u64 wmax = wave_u64max63(c[0]);

            if (lane == 63) exch[it & 1][wv] = wmax;
            __syncthreads();

            const ulonglong2* e = (const ulonglong2*)&exch[it & 1][0];
            const ulonglong2 E0 = e[0], E1 = e[1], E2 = e[2], E3 = e[3];
            u64 m01 = u64max(E0.x, E0.y), m23 = u64max(E1.x, E1.y);
            u64 m45 = u64max(E2.x, E2.y), m67 = u64max(E3.x, E3.y);
            const u64 m = u64max(u64max(m01, m23), u64max(m45, m67));
            const int bi = 4095 - (int)((unsigned)m & 0xFFFu);

            if (t == 0) fps_lds[it] = bi;
            const float4 cc = spts[bi];
            lx = cc.x; ly = cc.y; lz = cc.z;
        }
        __syncthreads();
        for (int j = t; j < NPOINT; j += 512) fps[b * NPOINT + j] = fps_lds[j];
    } else {
        // --------------------------- repulsion ---------------------------
        const int bb = blockIdx.x - NB;
        const int batch = bb >> 6;
        const int chunk = bb & 63;
        const float* base = pcd + (size_t)batch * NPTS * 3;

        for (int j = t; j < NPTS; j += 512) {
            const float x = base[j * 3 + 0], y = base[j * 3 + 1], z = base[j * 3 + 2];
            const float qs = (x * x + y * y) + z * z;
            spts[j] = make_float4(x, y, z, qs);
        }
        __syncthreads();

        const float h = 0.0005f;
        double acc = 0.0;

        for (int ii = 0; ii < 8; ++ii) {
            const int i = (chunk << 6) + (wv << 3) + ii;
            const float4 C = spts[i];
            const float cx = C.x, cy = C.y, cz = C.z, cs = C.w;
            float s0 = 3e38f, s1 = 3e38f, s2 = 3e38f, s3 = 3e38f;
            for (int bj = 0; bj < NPTS; bj += 64) {
                const int j = bj + lane;
                const float4 o = spts[j];
                const float dot = (cx * o.x + cy * o.y) + cz * o.z;
                const float d = fmaxf((cs + o.w) - 2.0f * dot, 0.0f);
                const bool q = (d < h) && (j != i);
                unsigned long long bal = __ballot(q);
                while (bal) {
                    const int src = __ffsll((unsigned long long)bal) - 1;
                    bal &= bal - 1;
                    const float dv = __shfl(d, src);
                    if (dv < s0) { s3 = s2; s2 = s1; s1 = s0; s0 = dv; }
                    else if (dv < s1) { s3 = s2; s2 = s1; s1 = dv; }
                    else if (dv < s2) { s3 = s2; s2 = dv; }
                    else if (dv < s3) { s3 = dv; }
                }
            }
            if (lane == 0) {
                if (s0 < h) acc += (double)(h - s0);
                if (s1 < h) acc += (double)(h - s1);
                if (s2 < h) acc += (double)(h - s2);
                if (s3 < h) acc += (double)(h - s3);
            }
        }
        if (lane == 0) wsum[wv] = acc;
        __syncthreads();
        if (t == 0) {
            double s = 0.0;
            for (int w = 0; w < 8; ++w) s += wsum[w];
            part[bb] = s;
        }
    }
}

// ---------------------------------------------------------------------------
// Ball query + uniform term, ALL 5 percentages fused into one scan.
// Block = 4 waves = 4 centers (one batch; 204%4==0 so no batch straddle),
// each wave computes d once per point and tests the 5 nested thresholds.
// ---------------------------------------------------------------------------
__global__ __launch_bounds__(256) void ball_kernel(const float* __restrict__ pcd,
                                                   const int* __restrict__ fps,
                                                   double* __restrict__ uvals,
                                                   BallParams P)
{
#pragma clang fp contract(off)
    __shared__ float4 spts[NPTS];          // 64 KiB: x,y,z,|q|^2
    __shared__ int wlist[4][5][52];        // per-wave, per-p index lists
    __shared__ float4 gpts[4][64];

    const int wave = threadIdx.x >> 6;
    const int lane = threadIdx.x & 63;
    const int c = blockIdx.x * 4 + wave;   // global center id
    const int b = c / NPOINT;
    const int m = c % NPOINT;

    const float* base = pcd + (size_t)b * NPTS * 3;
    for (int j = threadIdx.x; j < NPTS; j += 256) {
        const float x = base[j * 3 + 0], y = base[j * 3 + 1], z = base[j * 3 + 2];
        const float qs = (x * x + y * y) + z * z;
        spts[j] = make_float4(x, y, z, qs);
    }
    __syncthreads();

    const int ci = fps[b * NPOINT + m];
    const float4 C = spts[ci];
    const float cx = C.x, cy = C.y, cz = C.z, cs = C.w;

    int cnt[5] = {0, 0, 0, 0, 0};
    const u64 lmask = (1ull << lane) - 1ull;
    for (int bj = 0; bj < NPTS; bj += 64) {
        const int j = bj + lane;
        const float4 o = spts[j];
        const float dot = (cx * o.x + cy * o.y) + cz * o.z;
        const float d = fmaxf((cs + o.w) - 2.0f * dot, 0.0f);
#pragma unroll
        for (int p = 0; p < 5; ++p) {
            const bool q = d < P.thr[p];
            const u64 bal = __ballot(q);
            if (q) {
                const int pos = cnt[p] + __popcll(bal & lmask);
                if (pos < P.ns[p]) wlist[wave][p][pos] = j;
            }
            cnt[p] += __popcll(bal);
        }
    }

    // 5 sequential group phases (wave-local; within-wave LDS ordering suffices)
#pragma unroll
    for (int p = 0; p < 5; ++p) {
        const int nsample = P.ns[p];
        const int m_in = (cnt[p] < nsample) ? cnt[p] : nsample;   // >= 1
        const int gidx = wlist[wave][p][(lane < m_in) ? lane : 0];
        const float4 G = spts[gidx];
        gpts[wave][lane] = G;
        const float gx = G.x, gy = G.y, gz = G.z, gs = G.w;

        float m1 = 3.0e38f, m2 = 3.0e38f;
        for (int j = 0; j < nsample; ++j) {
            const float4 o = gpts[wave][j];
            const float dot = (gx * o.x + gy * o.y) + gz * o.z;
            const float d = fmaxf((gs + o.w) - 2.0f * dot, 0.0f);
            if (d < m1) { m2 = m1; m1 = d; }
            else if (d < m2) { m2 = d; }
        }
        float ud = (lane < nsample) ? fabsf(sqrtf(m2 + 1e-12f) + 1e-8f) : 0.0f;
        for (int off = 32; off; off >>= 1) ud += __shfl_xor(ud, off);
        if (lane == 0) {
            const float um   = ud / (float)nsample;
            const float diff = um - P.el;
            const float u    = (diff * diff) / P.denom;
            uvals[p * NCENT + c] = (double)u;
        }
    }
}

// ---------------------------------------------------------------------------
// Deterministic final reduction + loss assembly: 6 interleaved shuffle-tree
// sums, a single barrier.
// ---------------------------------------------------------------------------
__global__ __launch_bounds__(256) void final_kernel(const double* __restrict__ uvals,
                                                    const double* __restrict__ part,
                                                    float* __restrict__ out,
                                                    FinalParams F)
{
    __shared__ double red[6][4];
    const int t = threadIdx.x;
    const int lane = t & 63, wv = t >> 6;

    double s[6] = {0.0, 0.0, 0.0, 0.0, 0.0, 0.0};
    for (int c = t; c < NCENT; c += 256) {
        s[0] += uvals[0 * NCENT + c];
        s[1] += uvals[1 * NCENT + c];
        s[2] += uvals[2 * NCENT + c];
        s[3] += uvals[3 * NCENT + c];
        s[4] += uvals[4 * NCENT + c];
    }
    for (int c = t; c < NB * 64; c += 256) s[5] += part[c];

    for (int off = 32; off; off >>= 1) {
#pragma unroll
        for (int p = 0; p < 6; ++p) s[p] += __shfl_xor(s[p], off);
    }
    if (lane == 0) {
#pragma unroll
        for (int p = 0; p < 6; ++p) red[p][wv] = s[p];
    }
    __syncthreads();
    if (t == 0) {
        double sums[6];
#pragma unroll
        for (int p = 0; p < 6; ++p)
            sums[p] = ((red[p][0] + red[p][1]) + red[p][2]) + red[p][3];
        double loss = 0.0;
        loss += (sums[0] / (double)NCENT) * F.w[0];
        loss += (sums[1] / (double)NCENT) * F.w[1];
        loss += (sums[2] / (double)NCENT) * F.w[2];
        loss += (sums[3] / (double)NCENT) * F.w[3];
        loss += (sums[4] / (double)NCENT) * F.w[4];
        loss /= 5.0;
        const double rep = sums[5] / (double)(NB * NPTS * 4);
        out[0] = (float)(loss + rep);
    }
}

// ---------------------------------------------------------------------------
extern "C" void kernel_launch(void* const* d_in, const int* in_sizes, int n_in,
                              void* d_out, int out_size, void* d_ws, size_t ws_size,
                              hipStream_t stream)
{
    const float* pcd = (const float*)d_in[0];
    float* out = (float*)d_out;

    int*    fps   = (int*)d_ws;                                   // NB*NPOINT ints
    double* uvals = (double*)((char*)d_ws + 8192);                // 5*NCENT doubles
    double* repp  = (double*)((char*)d_ws + 8192 + (size_t)5 * NCENT * 8); // NB*64 doubles

    const double pv[5] = {0.004, 0.006, 0.008, 0.01, 0.012};
    const int    nsv[5] = {16, 24, 32, 40, 49};

    BallParams bp;
    FinalParams fp;
    for (int i = 0; i < 5; ++i) {
        const double r = sqrt(pv[i]);
        bp.thr[i] = (float)(r * r);
        bp.ns[i]  = nsv[i];
        const double w = pv[i] * 100.0;
        fp.w[i] = w * w;
    }
    const double el = sqrt(3.141592653589793 / 4096.0);
    bp.el    = (float)el;
    bp.denom = (float)(el + 1e-8);

    fused_fps_rep<<<NB + NB * 64, 512, 0, stream>>>(pcd, fps, repp);
    ball_kernel<<<NCENT / 4, 256, 0, stream>>>(pcd, fps, uvals, bp);
    final_kernel<<<1, 256, 0, stream>>>(uvals, repp, out, fp);
}